// Round 6
// baseline (225.838 us; speedup 1.0000x reference)
//
#include <hip/hip_runtime.h>
#include <hip/hip_bf16.h>

typedef __bf16 bf16_t;
typedef __bf16 bf16x8 __attribute__((ext_vector_type(8)));
typedef __bf16 bf16x4 __attribute__((ext_vector_type(4)));
typedef float f32x4 __attribute__((ext_vector_type(4)));

__device__ __forceinline__ bf16_t f2bf(float f) {
    __hip_bfloat16 h = __float2bfloat16(f);   // RNE
    return __builtin_bit_cast(bf16_t, h);
}

__device__ __forceinline__ float tanh_fast(float s) {
    float e2x = __expf(2.0f * s);
    return 1.0f - 2.0f * __builtin_amdgcn_rcpf(e2x + 1.0f);
}

// 16B-unit XOR swizzle within 64-unit groups (involution)
__device__ __forceinline__ int swz(int u) { return u ^ ((u >> 3) & 7); }
// LDS byte-address swizzle: spreads 1KB..8KB row strides over banks (involution)
__device__ __forceinline__ int actswz(int a) {
    return a ^ ((((a >> 10) ^ (a >> 13)) & 7) << 4);
}

#define GLD16(g, l)                                                        \
    __builtin_amdgcn_global_load_lds(                                      \
        (const __attribute__((address_space(1))) void*)(g),                \
        (__attribute__((address_space(3))) void*)(l), 16, 0, 0)

#define WAITV1() asm volatile("s_waitcnt vmcnt(1)" ::: "memory")
#define WAITV0() asm volatile("s_waitcnt vmcnt(0)" ::: "memory")
#define BAR() __builtin_amdgcn_s_barrier()

// ---------------------------------------------------------------------------
// Setup: blocks 0..7999 table f32->bf16; 8000..8063 Wfrag (MFMA frag order);
// 8064..8127 WFwT transpose (f32).
__global__ void __launch_bounds__(256) setup_kernel(const float* __restrict__ table,
                                                    const float* __restrict__ WRw,
                                                    const float* __restrict__ WFw,
                                                    bf16_t* __restrict__ tableBf,
                                                    bf16_t* __restrict__ Wfrag,
                                                    float* __restrict__ WFwT) {
    const int b = blockIdx.x, tid = threadIdx.x;
    if (b < 8000) {
        int i = b * 256 + tid;
        float4 v = ((const float4*)table)[i];
        bf16x4 o;
        o[0] = f2bf(v.x); o[1] = f2bf(v.y); o[2] = f2bf(v.z); o[3] = f2bf(v.w);
        ((bf16x4*)tableBf)[i] = o;
    } else if (b < 8064) {
        int gt = (b - 8000) * 256 + tid;        // 0..16383
        int n16 = gt >> 10, rem = gt & 1023;
        int kt = rem >> 6, ln = rem & 63;
        int r = n16 * 16 + (ln & 15);
        int c = kt * 32 + (ln >> 4) * 8;
        const float4* s = (const float4*)(WRw + (long)r * 512 + c);
        float4 v0 = s[0], v1 = s[1];
        bf16x8 o;
        o[0] = f2bf(v0.x); o[1] = f2bf(v0.y); o[2] = f2bf(v0.z); o[3] = f2bf(v0.w);
        o[4] = f2bf(v1.x); o[5] = f2bf(v1.y); o[6] = f2bf(v1.z); o[7] = f2bf(v1.w);
        *(bf16x8*)(Wfrag + (size_t)gt * 8) = o;
    } else {
        int i0 = (b - 8064) * 1024 + tid * 4;   // WFwT[k*256+t] = WFw[t*256+k]
        float4 v;
        v.x = WFw[((i0 + 0) & 255) * 256 + ((i0 + 0) >> 8)];
        v.y = WFw[((i0 + 1) & 255) * 256 + ((i0 + 1) >> 8)];
        v.z = WFw[((i0 + 2) & 255) * 256 + ((i0 + 2) >> 8)];
        v.w = WFw[((i0 + 3) & 255) * 256 + ((i0 + 3) >> 8)];
        *(float4*)(WFwT + i0) = v;
    }
}

// ---------------------------------------------------------------------------
// Fully fused tree: 256 blocks (one batch each), 512 threads (8 waves).
// Wave w owns output cols [32w, 32w+32) at EVERY level; W lives in VGPRs
// (wreg[2][16] bf16x8 frags). L1 runs in two 128-row halves whose outputs
// stay in LDS (bufX); L2 consumes each half immediately. L3..L9 operate
// in-place in act with stride-doubling layout. Head fused at the end.
__global__ void __launch_bounds__(512, 2) fused_kernel(const int* __restrict__ tokens,
                                                       const bf16_t* __restrict__ tableBf,
                                                       const bf16_t* __restrict__ Wfrag,
                                                       const float* __restrict__ bias,
                                                       const float* __restrict__ WFwT,
                                                       const float* __restrict__ WFb,
                                                       const float* __restrict__ WOw,
                                                       const float* __restrict__ WOb,
                                                       float* __restrict__ out) {
    __shared__ __align__(16) char stg[24576];    // 3 x 8KB A-staging
    __shared__ __align__(16) char bufX[65536];   // L1-out half: 64 A-rows x 1KB
    __shared__ __align__(16) char act[65536];    // L2-out + tail levels
    __shared__ float hid[256];

    const int tid = threadIdx.x, lane = tid & 63, w = tid >> 6;
    const int lr = lane & 15, g = lane >> 4, crow = g << 2;
    const f32x4 zero = {0.f, 0.f, 0.f, 0.f};

    float bvT[2];
#pragma unroll
    for (int nt = 0; nt < 2; ++nt) bvT[nt] = bias[(w << 5) + (nt << 4) + lr];

    // W fragments for this wave's 32 columns, all 16 K-steps: 64 VGPRs
    bf16x8 wreg[2][16];
#pragma unroll
    for (int nt = 0; nt < 2; ++nt)
#pragma unroll
        for (int kt = 0; kt < 16; ++kt)
            wreg[nt][kt] = *(const bf16x8*)(
                Wfrag + (size_t)((((w * 2 + nt) * 16 + kt) * 64 + lane)) * 8);

    // L1 staging geometry (8KB tile = 512 units of 16B; unit-swizzled source)
    const int us = (w << 6) + swz(lane);
    const int srow = us >> 2;              // A-row within half, 0..127
    const int scolE = (us & 3) << 3;       // elem offset 0,8,16,24
    char* dst = stg + (w << 10);
    int offA1[8];
#pragma unroll
    for (int mt = 0; mt < 8; ++mt)
        offA1[mt] = swz((((mt << 4) + lr) << 2) + g) << 4;

    // ================= L1 + L2, two halves ================================
#pragma unroll 1
    for (int h = 0; h < 2; ++h) {
        long mrow = (long)blockIdx.x * 256 + h * 128 + srow;
        int tok0 = tokens[2 * mrow], tok1 = tokens[2 * mrow + 1];
        const bf16_t* tLo = tableBf + (long)tok0 * 256 + scolE;
        const bf16_t* tHi = tableBf + (long)tok1 * 256 + scolE;

        auto stage = [&](int s, int kt) {
            const bf16_t* src = (kt < 8) ? (tLo + (kt << 5)) : (tHi + ((kt - 8) << 5));
            GLD16(src, dst + s * 8192);
        };

        f32x4 acc[8][2];
#pragma unroll
        for (int i = 0; i < 8; ++i) { acc[i][0] = zero; acc[i][1] = zero; }

        stage(0, 0); stage(1, 1);
        WAITV1(); BAR();
#pragma unroll
        for (int t = 0; t < 16; ++t) {
            if (t + 2 < 16) stage((t + 2) % 3, t + 2);
            const char* base = stg + (t % 3) * 8192;
            bf16x8 af[8];
#pragma unroll
            for (int mt = 0; mt < 8; ++mt) af[mt] = *(const bf16x8*)(base + offA1[mt]);
#pragma unroll
            for (int mt = 0; mt < 8; ++mt)
#pragma unroll
                for (int nt = 0; nt < 2; ++nt)
                    acc[mt][nt] = __builtin_amdgcn_mfma_f32_16x16x32_bf16(
                        af[mt], wreg[nt][t], acc[mt][nt], 0, 0, 0);
            if (t < 14)       { WAITV1(); BAR(); }
            else if (t == 14) { WAITV0(); BAR(); }
        }
        // L1 epilogue -> bufX: L1 row r at byte (r>>1)*1024 + (r&1)*512
#pragma unroll
        for (int nt = 0; nt < 2; ++nt) {
            int col = (w << 5) + (nt << 4) + lr;
#pragma unroll
            for (int mt = 0; mt < 8; ++mt)
#pragma unroll
                for (int rr = 0; rr < 4; ++rr) {
                    int r = (mt << 4) + crow + rr;
                    int a = ((r >> 1) << 10) + ((r & 1) << 9) + (col << 1);
                    *(bf16_t*)(bufX + actswz(a)) =
                        f2bf(tanh_fast(acc[mt][nt][rr] + bvT[nt]));
                }
        }
        __syncthreads();

        // L2 half: M=64 (out rows h*64..h*64+64), A rows = bufX 1KB rows
        f32x4 acc2[4][2];
#pragma unroll
        for (int i = 0; i < 4; ++i) { acc2[i][0] = zero; acc2[i][1] = zero; }
#pragma unroll
        for (int kt = 0; kt < 16; ++kt) {
#pragma unroll
            for (int mt = 0; mt < 4; ++mt) {
                int a = (((mt << 4) + lr) << 10) + (kt << 6) + (g << 4);
                bf16x8 af = *(const bf16x8*)(bufX + actswz(a));
#pragma unroll
                for (int nt = 0; nt < 2; ++nt)
                    acc2[mt][nt] = __builtin_amdgcn_mfma_f32_16x16x32_bf16(
                        af, wreg[nt][kt], acc2[mt][nt], 0, 0, 0);
            }
        }
        __syncthreads();       // all bufX reads done before next half overwrites
#pragma unroll
        for (int nt = 0; nt < 2; ++nt) {
            int col = (w << 5) + (nt << 4) + lr;
#pragma unroll
            for (int mt = 0; mt < 4; ++mt)
#pragma unroll
                for (int rr = 0; rr < 4; ++rr) {
                    int q = (h << 6) + (mt << 4) + crow + rr;   // 0..127
                    int a = (q << 9) + (col << 1);
                    *(bf16_t*)(act + actswz(a)) =
                        f2bf(tanh_fast(acc2[mt][nt][rr] + bvT[nt]));
                }
        }
        __syncthreads();
    }

    // ================= L3: M=64, A rows at 1KB stride, out at 1KB*q ========
    {
        f32x4 acc[4][2];
#pragma unroll
        for (int i = 0; i < 4; ++i) { acc[i][0] = zero; acc[i][1] = zero; }
#pragma unroll
        for (int kt = 0; kt < 16; ++kt)
#pragma unroll
            for (int mt = 0; mt < 4; ++mt) {
                int a = (((mt << 4) + lr) << 10) + (kt << 6) + (g << 4);
                bf16x8 af = *(const bf16x8*)(act + actswz(a));
#pragma unroll
                for (int nt = 0; nt < 2; ++nt)
                    acc[mt][nt] = __builtin_amdgcn_mfma_f32_16x16x32_bf16(
                        af, wreg[nt][kt], acc[mt][nt], 0, 0, 0);
            }
        __syncthreads();
#pragma unroll
        for (int nt = 0; nt < 2; ++nt) {
            int col = (w << 5) + (nt << 4) + lr;
#pragma unroll
            for (int mt = 0; mt < 4; ++mt)
#pragma unroll
                for (int rr = 0; rr < 4; ++rr) {
                    int q = (mt << 4) + crow + rr;              // 0..63
                    int a = (q << 10) + (col << 1);
                    *(bf16_t*)(act + actswz(a)) =
                        f2bf(tanh_fast(acc[mt][nt][rr] + bvT[nt]));
                }
        }
        __syncthreads();
    }

    // ================= L4: M=32, A row m = {2KB*m, +512} ∪ {2KB*m+1KB, +512}
    {
        f32x4 acc[2][2];
#pragma unroll
        for (int i = 0; i < 2; ++i) { acc[i][0] = zero; acc[i][1] = zero; }
#pragma unroll
        for (int kt = 0; kt < 16; ++kt)
#pragma unroll
            for (int mt = 0; mt < 2; ++mt) {
                int row = (mt << 4) + lr;                       // 0..31
                int a = (row << 11) + ((kt >= 8) ? 1024 : 0) + ((kt & 7) << 6) + (g << 4);
                bf16x8 af = *(const bf16x8*)(act + actswz(a));
#pragma unroll
                for (int nt = 0; nt < 2; ++nt)
                    acc[mt][nt] = __builtin_amdgcn_mfma_f32_16x16x32_bf16(
                        af, wreg[nt][kt], acc[mt][nt], 0, 0, 0);
            }
        __syncthreads();
#pragma unroll
        for (int nt = 0; nt < 2; ++nt) {
            int col = (w << 5) + (nt << 4) + lr;
#pragma unroll
            for (int mt = 0; mt < 2; ++mt)
#pragma unroll
                for (int rr = 0; rr < 4; ++rr) {
                    int q = (mt << 4) + crow + rr;              // 0..31
                    int a = (q << 11) + (col << 1);
                    *(bf16_t*)(act + actswz(a)) =
                        f2bf(tanh_fast(acc[mt][nt][rr] + bvT[nt]));
                }
        }
        __syncthreads();
    }

    // ================= L5..L9: M=16 padded, stride-doubling ================
#pragma unroll 1
    for (int lev = 0; lev < 5; ++lev) {
        const int sA = 4096 << lev;
        const int half_ = sA >> 1;
        f32x4 acc[2];
        acc[0] = zero; acc[1] = zero;
#pragma unroll
        for (int kt = 0; kt < 16; ++kt) {
            int a = (sA * lr + ((kt >= 8) ? half_ : 0) + ((kt & 7) << 6) + (g << 4)) & 65535;
            bf16x8 af = *(const bf16x8*)(act + actswz(a));
            acc[0] = __builtin_amdgcn_mfma_f32_16x16x32_bf16(af, wreg[0][kt], acc[0], 0, 0, 0);
            acc[1] = __builtin_amdgcn_mfma_f32_16x16x32_bf16(af, wreg[1][kt], acc[1], 0, 0, 0);
        }
        __syncthreads();
        const int valid = 16 >> lev;
#pragma unroll
        for (int nt = 0; nt < 2; ++nt) {
            int col = (w << 5) + (nt << 4) + lr;
#pragma unroll
            for (int rr = 0; rr < 4; ++rr) {
                int m0 = crow + rr;
                if (m0 < valid) {
                    int a = sA * m0 + (col << 1);
                    *(bf16_t*)(act + actswz(a)) =
                        f2bf(tanh_fast(acc[nt][rr] + bvT[nt]));
                }
            }
        }
        __syncthreads();
    }

    // ================= head: root = act[0..512) (swizzle-free region) ======
    if (tid < 256) {
        const bf16_t* root = (const bf16_t*)act;
        float s = WFb[tid];
#pragma unroll 8
        for (int k = 0; k < 256; ++k)
            s += (float)root[k] * WFwT[k * 256 + tid];
        hid[tid] = fmaxf(s, 0.0f);
    }
    __syncthreads();

    if (w < 5) {
        const float* wo = WOw + w * 256;
        float p = hid[lane] * wo[lane] + hid[lane + 64] * wo[lane + 64] +
                  hid[lane + 128] * wo[lane + 128] + hid[lane + 192] * wo[lane + 192];
#pragma unroll
        for (int off = 32; off > 0; off >>= 1) p += __shfl_down(p, off);
        if (lane == 0) out[(long)blockIdx.x * 5 + w] = p + WOb[w];
    }
}

// ---------------------------------------------------------------------------
extern "C" void kernel_launch(void* const* d_in, const int* in_sizes, int n_in,
                              void* d_out, int out_size, void* d_ws, size_t ws_size,
                              hipStream_t stream) {
    const int*   tokens = (const int*)d_in[0];
    const float* table  = (const float*)d_in[1];
    const float* WRw    = (const float*)d_in[2];
    const float* WRb    = (const float*)d_in[3];
    const float* WFw    = (const float*)d_in[4];
    const float* WFb    = (const float*)d_in[5];
    const float* WOw    = (const float*)d_in[6];
    const float* WOb    = (const float*)d_in[7];
    float* out = (float*)d_out;

    char* ws = (char*)d_ws;
    bf16_t* tableBf = (bf16_t*)ws;                        // 16.4 MB
    bf16_t* Wfrag = (bf16_t*)(ws + (size_t)20971520);     // 256 KB
    float*  WFwT  = (float*)(ws + (size_t)22020096);      // 256 KB

    setup_kernel<<<8128, 256, 0, stream>>>(table, WRw, WFw, tableBf, Wfrag, WFwT);
    fused_kernel<<<256, 512, 0, stream>>>(tokens, tableBf, Wfrag, WRb, WFwT,
                                          WFb, WOw, WOb, out);
}

// Round 7
// 206.763 us; speedup vs baseline: 1.0923x; 1.0923x over previous
//
#include <hip/hip_runtime.h>
#include <hip/hip_bf16.h>

typedef __bf16 bf16_t;
typedef __bf16 bf16x8 __attribute__((ext_vector_type(8)));
typedef __bf16 bf16x4 __attribute__((ext_vector_type(4)));
typedef float f32x4 __attribute__((ext_vector_type(4)));

__device__ __forceinline__ bf16_t f2bf(float f) {
    __hip_bfloat16 h = __float2bfloat16(f);   // RNE
    return __builtin_bit_cast(bf16_t, h);
}

__device__ __forceinline__ float tanh_fast(float s) {
    float e2x = __expf(2.0f * s);
    return 1.0f - 2.0f * __builtin_amdgcn_rcpf(e2x + 1.0f);
}

// 16B-unit XOR swizzle within 64-unit groups (involution)
__device__ __forceinline__ int swz(int u) { return u ^ ((u >> 3) & 7); }
// LDS byte-address swizzle: spreads 1KB..8KB row strides over banks (involution)
__device__ __forceinline__ int actswz(int a) {
    return a ^ ((((a >> 10) ^ (a >> 13)) & 7) << 4);
}

#define GLD16(g, l)                                                        \
    __builtin_amdgcn_global_load_lds(                                      \
        (const __attribute__((address_space(1))) void*)(g),                \
        (__attribute__((address_space(3))) void*)(l), 16, 0, 0)

#define WAITV3() asm volatile("s_waitcnt vmcnt(3)" ::: "memory")
#define WAITV0() asm volatile("s_waitcnt vmcnt(0)" ::: "memory")
#define BAR() __builtin_amdgcn_s_barrier()

// ---------------------------------------------------------------------------
// Setup: blocks 0..7999 table f32->bf16; 8000..8063 Wfrag (MFMA frag order);
// 8064..8127 WFwT transpose (f32).
__global__ void __launch_bounds__(256) setup_kernel(const float* __restrict__ table,
                                                    const float* __restrict__ WRw,
                                                    const float* __restrict__ WFw,
                                                    bf16_t* __restrict__ tableBf,
                                                    bf16_t* __restrict__ Wfrag,
                                                    float* __restrict__ WFwT) {
    const int b = blockIdx.x, tid = threadIdx.x;
    if (b < 8000) {
        int i = b * 256 + tid;
        float4 v = ((const float4*)table)[i];
        bf16x4 o;
        o[0] = f2bf(v.x); o[1] = f2bf(v.y); o[2] = f2bf(v.z); o[3] = f2bf(v.w);
        ((bf16x4*)tableBf)[i] = o;
    } else if (b < 8064) {
        int gt = (b - 8000) * 256 + tid;        // 0..16383
        int n16 = gt >> 10, rem = gt & 1023;
        int kt = rem >> 6, ln = rem & 63;
        int r = n16 * 16 + (ln & 15);
        int c = kt * 32 + (ln >> 4) * 8;
        const float4* s = (const float4*)(WRw + (long)r * 512 + c);
        float4 v0 = s[0], v1 = s[1];
        bf16x8 o;
        o[0] = f2bf(v0.x); o[1] = f2bf(v0.y); o[2] = f2bf(v0.z); o[3] = f2bf(v0.w);
        o[4] = f2bf(v1.x); o[5] = f2bf(v1.y); o[6] = f2bf(v1.z); o[7] = f2bf(v1.w);
        *(bf16x8*)(Wfrag + (size_t)gt * 8) = o;
    } else {
        int i0 = (b - 8064) * 1024 + tid * 4;   // WFwT[k*256+t] = WFw[t*256+k]
        float4 v;
        v.x = WFw[((i0 + 0) & 255) * 256 + ((i0 + 0) >> 8)];
        v.y = WFw[((i0 + 1) & 255) * 256 + ((i0 + 1) >> 8)];
        v.z = WFw[((i0 + 2) & 255) * 256 + ((i0 + 2) >> 8)];
        v.w = WFw[((i0 + 3) & 255) * 256 + ((i0 + 3) >> 8)];
        *(float4*)(WFwT + i0) = v;
    }
}

// ---------------------------------------------------------------------------
// Fully fused tree: 256 blocks (one batch each), 512 threads (8 waves).
// Wave w owns output cols [32w, 32w+32) at EVERY level. L1..L4 stream W
// fragments from global (L2-hot, ~16 VGPRs in flight); wreg[2][16] (128
// VGPRs) is loaded ONLY after L4 for the register-light L5..L9 levels —
// this keeps peak register demand < 256 (round 6 spilled 70MB to scratch).
__global__ void __launch_bounds__(512, 2) fused_kernel(const int* __restrict__ tokens,
                                                       const bf16_t* __restrict__ tableBf,
                                                       const bf16_t* __restrict__ Wfrag,
                                                       const float* __restrict__ bias,
                                                       const float* __restrict__ WFwT,
                                                       const float* __restrict__ WFb,
                                                       const float* __restrict__ WOw,
                                                       const float* __restrict__ WOb,
                                                       float* __restrict__ out) {
    __shared__ __align__(16) char stg[24576];    // 3 x 8KB A-staging
    __shared__ __align__(16) char bufX[65536];   // L1-out half: 64 A-rows x 1KB
    __shared__ __align__(16) char act[65536];    // L2-out + tail levels
    __shared__ float hid[256];

    const int tid = threadIdx.x, lane = tid & 63, w = tid >> 6;
    const int lr = lane & 15, g = lane >> 4, crow = g << 2;
    const f32x4 zero = {0.f, 0.f, 0.f, 0.f};

    float bvT[2];
#pragma unroll
    for (int nt = 0; nt < 2; ++nt) bvT[nt] = bias[(w << 5) + (nt << 4) + lr];

    // W fragment source: frag(kt,nt) of wave w = wfW + nt*8192 + kt*512
    const bf16_t* wfW = Wfrag + (size_t)w * 16384 + (size_t)lane * 8;
    auto ldW = [&](int kt, int nt) {
        return *(const bf16x8*)(wfW + nt * 8192 + kt * 512);
    };

    // L1 staging geometry (8KB tile = 512 units of 16B; unit-swizzled source)
    const int us = (w << 6) + swz(lane);
    const int srow = us >> 2;              // A-row within half, 0..127
    const int scolE = (us & 3) << 3;       // elem offset 0,8,16,24
    char* dst = stg + (w << 10);
    int offA1[8];
#pragma unroll
    for (int mt = 0; mt < 8; ++mt)
        offA1[mt] = swz((((mt << 4) + lr) << 2) + g) << 4;

    // ================= L1 + L2, two halves ================================
#pragma unroll 1
    for (int h = 0; h < 2; ++h) {
        long mrow = (long)blockIdx.x * 256 + h * 128 + srow;
        int tok0 = tokens[2 * mrow], tok1 = tokens[2 * mrow + 1];
        const bf16_t* tLo = tableBf + (long)tok0 * 256 + scolE;
        const bf16_t* tHi = tableBf + (long)tok1 * 256 + scolE;

        auto stage = [&](int s, int kt) {
            const bf16_t* src = (kt < 8) ? (tLo + (kt << 5)) : (tHi + ((kt - 8) << 5));
            GLD16(src, dst + s * 8192);
        };

        f32x4 acc[8][2];
#pragma unroll
        for (int i = 0; i < 8; ++i) { acc[i][0] = zero; acc[i][1] = zero; }

        stage(0, 0); stage(1, 1);
        bf16x8 wfa = ldW(0, 0), wfb = ldW(0, 1);
        WAITV3(); BAR();                    // S(0) landed; {S1,Wa0,Wb0} in flight
#pragma unroll
        for (int t = 0; t < 16; ++t) {
            bf16x8 wfa_n, wfb_n;
            if (t + 1 < 16) { wfa_n = ldW(t + 1, 0); wfb_n = ldW(t + 1, 1); }
            if (t + 2 < 16) stage((t + 2) % 3, t + 2);
            const char* base = stg + (t % 3) * 8192;
            bf16x8 af[8];
#pragma unroll
            for (int mt = 0; mt < 8; ++mt) af[mt] = *(const bf16x8*)(base + offA1[mt]);
#pragma unroll
            for (int mt = 0; mt < 8; ++mt) {
                acc[mt][0] = __builtin_amdgcn_mfma_f32_16x16x32_bf16(af[mt], wfa, acc[mt][0], 0, 0, 0);
                acc[mt][1] = __builtin_amdgcn_mfma_f32_16x16x32_bf16(af[mt], wfb, acc[mt][1], 0, 0, 0);
            }
            if (t < 14)       { WAITV3(); BAR(); }   // S(t+1) landed, 3 newest in flight
            else if (t == 14) { WAITV0(); BAR(); }
            wfa = wfa_n; wfb = wfb_n;
        }
        // L1 epilogue -> bufX: L1 row r at byte (r>>1)*1024 + (r&1)*512
#pragma unroll
        for (int nt = 0; nt < 2; ++nt) {
            int col = (w << 5) + (nt << 4) + lr;
#pragma unroll
            for (int mt = 0; mt < 8; ++mt)
#pragma unroll
                for (int rr = 0; rr < 4; ++rr) {
                    int r = (mt << 4) + crow + rr;
                    int a = ((r >> 1) << 10) + ((r & 1) << 9) + (col << 1);
                    *(bf16_t*)(bufX + actswz(a)) =
                        f2bf(tanh_fast(acc[mt][nt][rr] + bvT[nt]));
                }
        }
        __syncthreads();

        // L2 half: M=64 (out rows h*64..), A = bufX 1KB rows, W streamed
        f32x4 acc2[4][2];
#pragma unroll
        for (int i = 0; i < 4; ++i) { acc2[i][0] = zero; acc2[i][1] = zero; }
#pragma unroll
        for (int kt = 0; kt < 16; ++kt) {
            bf16x8 wa = ldW(kt, 0), wb = ldW(kt, 1);
#pragma unroll
            for (int mt = 0; mt < 4; ++mt) {
                int a = (((mt << 4) + lr) << 10) + (kt << 6) + (g << 4);
                bf16x8 af = *(const bf16x8*)(bufX + actswz(a));
                acc2[mt][0] = __builtin_amdgcn_mfma_f32_16x16x32_bf16(af, wa, acc2[mt][0], 0, 0, 0);
                acc2[mt][1] = __builtin_amdgcn_mfma_f32_16x16x32_bf16(af, wb, acc2[mt][1], 0, 0, 0);
            }
        }
        __syncthreads();       // all bufX reads done before next half overwrites
#pragma unroll
        for (int nt = 0; nt < 2; ++nt) {
            int col = (w << 5) + (nt << 4) + lr;
#pragma unroll
            for (int mt = 0; mt < 4; ++mt)
#pragma unroll
                for (int rr = 0; rr < 4; ++rr) {
                    int q = (h << 6) + (mt << 4) + crow + rr;   // 0..127
                    int a = (q << 9) + (col << 1);
                    *(bf16_t*)(act + actswz(a)) =
                        f2bf(tanh_fast(acc2[mt][nt][rr] + bvT[nt]));
                }
        }
        __syncthreads();
    }

    // ================= L3: M=64, A rows at 1KB stride, W streamed ==========
    {
        f32x4 acc[4][2];
#pragma unroll
        for (int i = 0; i < 4; ++i) { acc[i][0] = zero; acc[i][1] = zero; }
#pragma unroll
        for (int kt = 0; kt < 16; ++kt) {
            bf16x8 wa = ldW(kt, 0), wb = ldW(kt, 1);
#pragma unroll
            for (int mt = 0; mt < 4; ++mt) {
                int a = (((mt << 4) + lr) << 10) + (kt << 6) + (g << 4);
                bf16x8 af = *(const bf16x8*)(act + actswz(a));
                acc[mt][0] = __builtin_amdgcn_mfma_f32_16x16x32_bf16(af, wa, acc[mt][0], 0, 0, 0);
                acc[mt][1] = __builtin_amdgcn_mfma_f32_16x16x32_bf16(af, wb, acc[mt][1], 0, 0, 0);
            }
        }
        __syncthreads();
#pragma unroll
        for (int nt = 0; nt < 2; ++nt) {
            int col = (w << 5) + (nt << 4) + lr;
#pragma unroll
            for (int mt = 0; mt < 4; ++mt)
#pragma unroll
                for (int rr = 0; rr < 4; ++rr) {
                    int q = (mt << 4) + crow + rr;              // 0..63
                    int a = (q << 10) + (col << 1);
                    *(bf16_t*)(act + actswz(a)) =
                        f2bf(tanh_fast(acc[mt][nt][rr] + bvT[nt]));
                }
        }
        __syncthreads();
    }

    // ================= L4: M=32, W streamed ================================
    {
        f32x4 acc[2][2];
#pragma unroll
        for (int i = 0; i < 2; ++i) { acc[i][0] = zero; acc[i][1] = zero; }
#pragma unroll
        for (int kt = 0; kt < 16; ++kt) {
            bf16x8 wa = ldW(kt, 0), wb = ldW(kt, 1);
#pragma unroll
            for (int mt = 0; mt < 2; ++mt) {
                int row = (mt << 4) + lr;                       // 0..31
                int a = (row << 11) + ((kt >= 8) ? 1024 : 0) + ((kt & 7) << 6) + (g << 4);
                bf16x8 af = *(const bf16x8*)(act + actswz(a));
                acc[mt][0] = __builtin_amdgcn_mfma_f32_16x16x32_bf16(af, wa, acc[mt][0], 0, 0, 0);
                acc[mt][1] = __builtin_amdgcn_mfma_f32_16x16x32_bf16(af, wb, acc[mt][1], 0, 0, 0);
            }
        }
        __syncthreads();
#pragma unroll
        for (int nt = 0; nt < 2; ++nt) {
            int col = (w << 5) + (nt << 4) + lr;
#pragma unroll
            for (int mt = 0; mt < 2; ++mt)
#pragma unroll
                for (int rr = 0; rr < 4; ++rr) {
                    int q = (mt << 4) + crow + rr;              // 0..31
                    int a = (q << 11) + (col << 1);
                    *(bf16_t*)(act + actswz(a)) =
                        f2bf(tanh_fast(acc[mt][nt][rr] + bvT[nt]));
                }
        }
        __syncthreads();
    }

    // ================= L5..L9: W now loaded into registers =================
    {
        bf16x8 wreg[2][16];
#pragma unroll
        for (int nt = 0; nt < 2; ++nt)
#pragma unroll
            for (int kt = 0; kt < 16; ++kt) wreg[nt][kt] = ldW(kt, nt);

#pragma unroll 1
        for (int lev = 0; lev < 5; ++lev) {
            const int sA = 4096 << lev;
            const int half_ = sA >> 1;
            f32x4 acc[2];
            acc[0] = zero; acc[1] = zero;
#pragma unroll
            for (int kt = 0; kt < 16; ++kt) {
                int a = (sA * lr + ((kt >= 8) ? half_ : 0) + ((kt & 7) << 6) + (g << 4)) & 65535;
                bf16x8 af = *(const bf16x8*)(act + actswz(a));
                acc[0] = __builtin_amdgcn_mfma_f32_16x16x32_bf16(af, wreg[0][kt], acc[0], 0, 0, 0);
                acc[1] = __builtin_amdgcn_mfma_f32_16x16x32_bf16(af, wreg[1][kt], acc[1], 0, 0, 0);
            }
            __syncthreads();
            const int valid = 16 >> lev;
#pragma unroll
            for (int nt = 0; nt < 2; ++nt) {
                int col = (w << 5) + (nt << 4) + lr;
#pragma unroll
                for (int rr = 0; rr < 4; ++rr) {
                    int m0 = crow + rr;
                    if (m0 < valid) {
                        int a = sA * m0 + (col << 1);
                        *(bf16_t*)(act + actswz(a)) =
                            f2bf(tanh_fast(acc[nt][rr] + bvT[nt]));
                    }
                }
            }
            __syncthreads();
        }
    }

    // ================= head: root = act[0..512) (swizzle-free region) ======
    if (tid < 256) {
        const bf16_t* root = (const bf16_t*)act;
        float s = WFb[tid];
#pragma unroll 8
        for (int k = 0; k < 256; ++k)
            s += (float)root[k] * WFwT[k * 256 + tid];
        hid[tid] = fmaxf(s, 0.0f);
    }
    __syncthreads();

    if (w < 5) {
        const float* wo = WOw + w * 256;
        float p = hid[lane] * wo[lane] + hid[lane + 64] * wo[lane + 64] +
                  hid[lane + 128] * wo[lane + 128] + hid[lane + 192] * wo[lane + 192];
#pragma unroll
        for (int off = 32; off > 0; off >>= 1) p += __shfl_down(p, off);
        if (lane == 0) out[(long)blockIdx.x * 5 + w] = p + WOb[w];
    }
}

// ---------------------------------------------------------------------------
extern "C" void kernel_launch(void* const* d_in, const int* in_sizes, int n_in,
                              void* d_out, int out_size, void* d_ws, size_t ws_size,
                              hipStream_t stream) {
    const int*   tokens = (const int*)d_in[0];
    const float* table  = (const float*)d_in[1];
    const float* WRw    = (const float*)d_in[2];
    const float* WRb    = (const float*)d_in[3];
    const float* WFw    = (const float*)d_in[4];
    const float* WFb    = (const float*)d_in[5];
    const float* WOw    = (const float*)d_in[6];
    const float* WOb    = (const float*)d_in[7];
    float* out = (float*)d_out;

    char* ws = (char*)d_ws;
    bf16_t* tableBf = (bf16_t*)ws;                        // 16.4 MB
    bf16_t* Wfrag = (bf16_t*)(ws + (size_t)20971520);     // 256 KB
    float*  WFwT  = (float*)(ws + (size_t)22020096);      // 256 KB

    setup_kernel<<<8128, 256, 0, stream>>>(table, WRw, WFw, tableBf, Wfrag, WFwT);
    fused_kernel<<<256, 512, 0, stream>>>(tokens, tableBf, Wfrag, WRb, WFwT,
                                          WFb, WOw, WOb, out);
}

// Round 8
// 205.481 us; speedup vs baseline: 1.0991x; 1.0062x over previous
//
#include <hip/hip_runtime.h>
#include <hip/hip_bf16.h>

typedef __bf16 bf16_t;
typedef __bf16 bf16x8 __attribute__((ext_vector_type(8)));
typedef __bf16 bf16x4 __attribute__((ext_vector_type(4)));
typedef float f32x4 __attribute__((ext_vector_type(4)));

__device__ __forceinline__ bf16_t f2bf(float f) {
    __hip_bfloat16 h = __float2bfloat16(f);   // RNE
    return __builtin_bit_cast(bf16_t, h);
}

__device__ __forceinline__ float tanh_fast(float s) {
    float e2x = __expf(2.0f * s);
    return 1.0f - 2.0f * __builtin_amdgcn_rcpf(e2x + 1.0f);
}

// 16B-unit XOR swizzle within 64-unit groups (involution)
__device__ __forceinline__ int swz(int u) { return u ^ ((u >> 3) & 7); }
// LDS byte-address swizzle: spreads 1KB..8KB row strides over banks (involution)
__device__ __forceinline__ int actswz(int a) {
    return a ^ ((((a >> 10) ^ (a >> 13)) & 7) << 4);
}

#define GLD16(g, l)                                                        \
    __builtin_amdgcn_global_load_lds(                                      \
        (const __attribute__((address_space(1))) void*)(g),                \
        (__attribute__((address_space(3))) void*)(l), 16, 0, 0)

#define WAITV3() asm volatile("s_waitcnt vmcnt(3)" ::: "memory")
#define WAITV0() asm volatile("s_waitcnt vmcnt(0)" ::: "memory")
#define BAR() __builtin_amdgcn_s_barrier()

// ---------------------------------------------------------------------------
// Setup: blocks 0..7999 table f32->bf16; 8000..8063 Wfrag (MFMA frag order);
// 8064..8127 WFwT transpose (f32).
__global__ void __launch_bounds__(256) setup_kernel(const float* __restrict__ table,
                                                    const float* __restrict__ WRw,
                                                    const float* __restrict__ WFw,
                                                    bf16_t* __restrict__ tableBf,
                                                    bf16_t* __restrict__ Wfrag,
                                                    float* __restrict__ WFwT) {
    const int b = blockIdx.x, tid = threadIdx.x;
    if (b < 8000) {
        int i = b * 256 + tid;
        float4 v = ((const float4*)table)[i];
        bf16x4 o;
        o[0] = f2bf(v.x); o[1] = f2bf(v.y); o[2] = f2bf(v.z); o[3] = f2bf(v.w);
        ((bf16x4*)tableBf)[i] = o;
    } else if (b < 8064) {
        int gt = (b - 8000) * 256 + tid;        // 0..16383
        int n16 = gt >> 10, rem = gt & 1023;
        int kt = rem >> 6, ln = rem & 63;
        int r = n16 * 16 + (ln & 15);
        int c = kt * 32 + (ln >> 4) * 8;
        const float4* s = (const float4*)(WRw + (long)r * 512 + c);
        float4 v0 = s[0], v1 = s[1];
        bf16x8 o;
        o[0] = f2bf(v0.x); o[1] = f2bf(v0.y); o[2] = f2bf(v0.z); o[3] = f2bf(v0.w);
        o[4] = f2bf(v1.x); o[5] = f2bf(v1.y); o[6] = f2bf(v1.z); o[7] = f2bf(v1.w);
        *(bf16x8*)(Wfrag + (size_t)gt * 8) = o;
    } else {
        int i0 = (b - 8064) * 1024 + tid * 4;   // WFwT[k*256+t] = WFw[t*256+k]
        float4 v;
        v.x = WFw[((i0 + 0) & 255) * 256 + ((i0 + 0) >> 8)];
        v.y = WFw[((i0 + 1) & 255) * 256 + ((i0 + 1) >> 8)];
        v.z = WFw[((i0 + 2) & 255) * 256 + ((i0 + 2) >> 8)];
        v.w = WFw[((i0 + 3) & 255) * 256 + ((i0 + 3) >> 8)];
        *(float4*)(WFwT + i0) = v;
    }
}

// ---------------------------------------------------------------------------
// Fully fused tree: 256 blocks (one batch each), 512 threads (8 waves).
// Wave w owns output cols [32w, 32w+32) at EVERY level. L1..L4 stream W
// fragments from global (L2-hot, ~16 VGPRs in flight); wreg[2][16] (128
// VGPRs) loaded only after L4.
// __launch_bounds__(512, 1): LDS (153KB) already caps at 1 block/CU, and the
// ",2" variant force-capped VGPRs at 128 -> 44MB scratch spill (rounds 6-7).
__global__ void __launch_bounds__(512, 1) fused_kernel(const int* __restrict__ tokens,
                                                       const bf16_t* __restrict__ tableBf,
                                                       const bf16_t* __restrict__ Wfrag,
                                                       const float* __restrict__ bias,
                                                       const float* __restrict__ WFwT,
                                                       const float* __restrict__ WFb,
                                                       const float* __restrict__ WOw,
                                                       const float* __restrict__ WOb,
                                                       float* __restrict__ out) {
    __shared__ __align__(16) char stg[24576];    // 3 x 8KB A-staging
    __shared__ __align__(16) char bufX[65536];   // L1-out half: 64 A-rows x 1KB
    __shared__ __align__(16) char act[65536];    // L2-out + tail levels
    __shared__ float hid[256];

    const int tid = threadIdx.x, lane = tid & 63, w = tid >> 6;
    const int lr = lane & 15, g = lane >> 4, crow = g << 2;
    const f32x4 zero = {0.f, 0.f, 0.f, 0.f};

    float bvT[2];
#pragma unroll
    for (int nt = 0; nt < 2; ++nt) bvT[nt] = bias[(w << 5) + (nt << 4) + lr];

    // W fragment source: frag(kt,nt) of wave w = wfW + nt*8192 + kt*512
    const bf16_t* wfW = Wfrag + (size_t)w * 16384 + (size_t)lane * 8;
    auto ldW = [&](int kt, int nt) {
        return *(const bf16x8*)(wfW + nt * 8192 + kt * 512);
    };

    // L1 staging geometry (8KB tile = 512 units of 16B; unit-swizzled source)
    const int us = (w << 6) + swz(lane);
    const int srow = us >> 2;              // A-row within half, 0..127
    const int scolE = (us & 3) << 3;       // elem offset 0,8,16,24
    char* dst = stg + (w << 10);
    int offA1[8];
#pragma unroll
    for (int mt = 0; mt < 8; ++mt)
        offA1[mt] = swz((((mt << 4) + lr) << 2) + g) << 4;

    // ================= L1 + L2, two halves ================================
#pragma unroll 1
    for (int h = 0; h < 2; ++h) {
        long mrow = (long)blockIdx.x * 256 + h * 128 + srow;
        int tok0 = tokens[2 * mrow], tok1 = tokens[2 * mrow + 1];
        const bf16_t* tLo = tableBf + (long)tok0 * 256 + scolE;
        const bf16_t* tHi = tableBf + (long)tok1 * 256 + scolE;

        auto stage = [&](int s, int kt) {
            const bf16_t* src = (kt < 8) ? (tLo + (kt << 5)) : (tHi + ((kt - 8) << 5));
            GLD16(src, dst + s * 8192);
        };

        f32x4 acc[8][2];
#pragma unroll
        for (int i = 0; i < 8; ++i) { acc[i][0] = zero; acc[i][1] = zero; }

        stage(0, 0); stage(1, 1);
        bf16x8 wfa = ldW(0, 0), wfb = ldW(0, 1);
        WAITV3(); BAR();                    // S(0) landed; {S1,Wa0,Wb0} in flight
#pragma unroll
        for (int t = 0; t < 16; ++t) {
            bf16x8 wfa_n, wfb_n;
            if (t + 1 < 16) { wfa_n = ldW(t + 1, 0); wfb_n = ldW(t + 1, 1); }
            if (t + 2 < 16) stage((t + 2) % 3, t + 2);
            const char* base = stg + (t % 3) * 8192;
            bf16x8 af[8];
#pragma unroll
            for (int mt = 0; mt < 8; ++mt) af[mt] = *(const bf16x8*)(base + offA1[mt]);
#pragma unroll
            for (int mt = 0; mt < 8; ++mt) {
                acc[mt][0] = __builtin_amdgcn_mfma_f32_16x16x32_bf16(af[mt], wfa, acc[mt][0], 0, 0, 0);
                acc[mt][1] = __builtin_amdgcn_mfma_f32_16x16x32_bf16(af[mt], wfb, acc[mt][1], 0, 0, 0);
            }
            if (t < 14)       { WAITV3(); BAR(); }   // S(t+1) landed, 3 newest in flight
            else if (t == 14) { WAITV0(); BAR(); }
            wfa = wfa_n; wfb = wfb_n;
        }
        // L1 epilogue -> bufX: L1 row r at byte (r>>1)*1024 + (r&1)*512
#pragma unroll
        for (int nt = 0; nt < 2; ++nt) {
            int col = (w << 5) + (nt << 4) + lr;
#pragma unroll
            for (int mt = 0; mt < 8; ++mt)
#pragma unroll
                for (int rr = 0; rr < 4; ++rr) {
                    int r = (mt << 4) + crow + rr;
                    int a = ((r >> 1) << 10) + ((r & 1) << 9) + (col << 1);
                    *(bf16_t*)(bufX + actswz(a)) =
                        f2bf(tanh_fast(acc[mt][nt][rr] + bvT[nt]));
                }
        }
        __syncthreads();

        // L2 half: M=64 (out rows h*64..), A = bufX 1KB rows, W streamed
        f32x4 acc2[4][2];
#pragma unroll
        for (int i = 0; i < 4; ++i) { acc2[i][0] = zero; acc2[i][1] = zero; }
#pragma unroll
        for (int kt = 0; kt < 16; ++kt) {
            bf16x8 wa = ldW(kt, 0), wb = ldW(kt, 1);
#pragma unroll
            for (int mt = 0; mt < 4; ++mt) {
                int a = (((mt << 4) + lr) << 10) + (kt << 6) + (g << 4);
                bf16x8 af = *(const bf16x8*)(bufX + actswz(a));
                acc2[mt][0] = __builtin_amdgcn_mfma_f32_16x16x32_bf16(af, wa, acc2[mt][0], 0, 0, 0);
                acc2[mt][1] = __builtin_amdgcn_mfma_f32_16x16x32_bf16(af, wb, acc2[mt][1], 0, 0, 0);
            }
        }
        __syncthreads();       // all bufX reads done before next half overwrites
#pragma unroll
        for (int nt = 0; nt < 2; ++nt) {
            int col = (w << 5) + (nt << 4) + lr;
#pragma unroll
            for (int mt = 0; mt < 4; ++mt)
#pragma unroll
                for (int rr = 0; rr < 4; ++rr) {
                    int q = (h << 6) + (mt << 4) + crow + rr;   // 0..127
                    int a = (q << 9) + (col << 1);
                    *(bf16_t*)(act + actswz(a)) =
                        f2bf(tanh_fast(acc2[mt][nt][rr] + bvT[nt]));
                }
        }
        __syncthreads();
    }

    // ================= L3: M=64, A rows at 1KB stride, W streamed ==========
    {
        f32x4 acc[4][2];
#pragma unroll
        for (int i = 0; i < 4; ++i) { acc[i][0] = zero; acc[i][1] = zero; }
#pragma unroll
        for (int kt = 0; kt < 16; ++kt) {
            bf16x8 wa = ldW(kt, 0), wb = ldW(kt, 1);
#pragma unroll
            for (int mt = 0; mt < 4; ++mt) {
                int a = (((mt << 4) + lr) << 10) + (kt << 6) + (g << 4);
                bf16x8 af = *(const bf16x8*)(act + actswz(a));
                acc[mt][0] = __builtin_amdgcn_mfma_f32_16x16x32_bf16(af, wa, acc[mt][0], 0, 0, 0);
                acc[mt][1] = __builtin_amdgcn_mfma_f32_16x16x32_bf16(af, wb, acc[mt][1], 0, 0, 0);
            }
        }
        __syncthreads();
#pragma unroll
        for (int nt = 0; nt < 2; ++nt) {
            int col = (w << 5) + (nt << 4) + lr;
#pragma unroll
            for (int mt = 0; mt < 4; ++mt)
#pragma unroll
                for (int rr = 0; rr < 4; ++rr) {
                    int q = (mt << 4) + crow + rr;              // 0..63
                    int a = (q << 10) + (col << 1);
                    *(bf16_t*)(act + actswz(a)) =
                        f2bf(tanh_fast(acc[mt][nt][rr] + bvT[nt]));
                }
        }
        __syncthreads();
    }

    // ================= L4: M=32, W streamed ================================
    {
        f32x4 acc[2][2];
#pragma unroll
        for (int i = 0; i < 2; ++i) { acc[i][0] = zero; acc[i][1] = zero; }
#pragma unroll
        for (int kt = 0; kt < 16; ++kt) {
            bf16x8 wa = ldW(kt, 0), wb = ldW(kt, 1);
#pragma unroll
            for (int mt = 0; mt < 2; ++mt) {
                int row = (mt << 4) + lr;                       // 0..31
                int a = (row << 11) + ((kt >= 8) ? 1024 : 0) + ((kt & 7) << 6) + (g << 4);
                bf16x8 af = *(const bf16x8*)(act + actswz(a));
                acc[mt][0] = __builtin_amdgcn_mfma_f32_16x16x32_bf16(af, wa, acc[mt][0], 0, 0, 0);
                acc[mt][1] = __builtin_amdgcn_mfma_f32_16x16x32_bf16(af, wb, acc[mt][1], 0, 0, 0);
            }
        }
        __syncthreads();
#pragma unroll
        for (int nt = 0; nt < 2; ++nt) {
            int col = (w << 5) + (nt << 4) + lr;
#pragma unroll
            for (int mt = 0; mt < 2; ++mt)
#pragma unroll
                for (int rr = 0; rr < 4; ++rr) {
                    int q = (mt << 4) + crow + rr;              // 0..31
                    int a = (q << 11) + (col << 1);
                    *(bf16_t*)(act + actswz(a)) =
                        f2bf(tanh_fast(acc[mt][nt][rr] + bvT[nt]));
                }
        }
        __syncthreads();
    }

    // ================= L5..L9: W now loaded into registers =================
    {
        bf16x8 wreg[2][16];
#pragma unroll
        for (int nt = 0; nt < 2; ++nt)
#pragma unroll
            for (int kt = 0; kt < 16; ++kt) wreg[nt][kt] = ldW(kt, nt);

#pragma unroll 1
        for (int lev = 0; lev < 5; ++lev) {
            const int sA = 4096 << lev;
            const int half_ = sA >> 1;
            f32x4 acc[2];
            acc[0] = zero; acc[1] = zero;
#pragma unroll
            for (int kt = 0; kt < 16; ++kt) {
                int a = (sA * lr + ((kt >= 8) ? half_ : 0) + ((kt & 7) << 6) + (g << 4)) & 65535;
                bf16x8 af = *(const bf16x8*)(act + actswz(a));
                acc[0] = __builtin_amdgcn_mfma_f32_16x16x32_bf16(af, wreg[0][kt], acc[0], 0, 0, 0);
                acc[1] = __builtin_amdgcn_mfma_f32_16x16x32_bf16(af, wreg[1][kt], acc[1], 0, 0, 0);
            }
            __syncthreads();
            const int valid = 16 >> lev;
#pragma unroll
            for (int nt = 0; nt < 2; ++nt) {
                int col = (w << 5) + (nt << 4) + lr;
#pragma unroll
                for (int rr = 0; rr < 4; ++rr) {
                    int m0 = crow + rr;
                    if (m0 < valid) {
                        int a = sA * m0 + (col << 1);
                        *(bf16_t*)(act + actswz(a)) =
                            f2bf(tanh_fast(acc[nt][rr] + bvT[nt]));
                    }
                }
            }
            __syncthreads();
        }
    }

    // ================= head: root = act[0..512) (swizzle-free region) ======
    if (tid < 256) {
        const bf16_t* root = (const bf16_t*)act;
        float s = WFb[tid];
#pragma unroll 8
        for (int k = 0; k < 256; ++k)
            s += (float)root[k] * WFwT[k * 256 + tid];
        hid[tid] = fmaxf(s, 0.0f);
    }
    __syncthreads();

    if (w < 5) {
        const float* wo = WOw + w * 256;
        float p = hid[lane] * wo[lane] + hid[lane + 64] * wo[lane + 64] +
                  hid[lane + 128] * wo[lane + 128] + hid[lane + 192] * wo[lane + 192];
#pragma unroll
        for (int off = 32; off > 0; off >>= 1) p += __shfl_down(p, off);
        if (lane == 0) out[(long)blockIdx.x * 5 + w] = p + WOb[w];
    }
}

// ---------------------------------------------------------------------------
extern "C" void kernel_launch(void* const* d_in, const int* in_sizes, int n_in,
                              void* d_out, int out_size, void* d_ws, size_t ws_size,
                              hipStream_t stream) {
    const int*   tokens = (const int*)d_in[0];
    const float* table  = (const float*)d_in[1];
    const float* WRw    = (const float*)d_in[2];
    const float* WRb    = (const float*)d_in[3];
    const float* WFw    = (const float*)d_in[4];
    const float* WFb    = (const float*)d_in[5];
    const float* WOw    = (const float*)d_in[6];
    const float* WOb    = (const float*)d_in[7];
    float* out = (float*)d_out;

    char* ws = (char*)d_ws;
    bf16_t* tableBf = (bf16_t*)ws;                        // 16.4 MB
    bf16_t* Wfrag = (bf16_t*)(ws + (size_t)20971520);     // 256 KB
    float*  WFwT  = (float*)(ws + (size_t)22020096);      // 256 KB

    setup_kernel<<<8128, 256, 0, stream>>>(table, WRw, WFw, tableBf, Wfrag, WFwT);
    fused_kernel<<<256, 512, 0, stream>>>(tokens, tableBf, Wfrag, WRb, WFwT,
                                          WFb, WOw, WOb, out);
}

// Round 10
// 204.384 us; speedup vs baseline: 1.1050x; 1.0054x over previous
//
#include <hip/hip_runtime.h>
#include <hip/hip_bf16.h>

typedef __bf16 bf16_t;
typedef __bf16 bf16x8 __attribute__((ext_vector_type(8)));
typedef __bf16 bf16x4 __attribute__((ext_vector_type(4)));
typedef float f32x4 __attribute__((ext_vector_type(4)));

__device__ __forceinline__ bf16_t f2bf(float f) {
    __hip_bfloat16 h = __float2bfloat16(f);   // RNE
    return __builtin_bit_cast(bf16_t, h);
}

__device__ __forceinline__ float tanh_fast(float s) {
    float e2x = __expf(2.0f * s);
    return 1.0f - 2.0f * __builtin_amdgcn_rcpf(e2x + 1.0f);
}

// 16B-unit XOR swizzle within 64-unit groups (involution)
__device__ __forceinline__ int swz(int u) { return u ^ ((u >> 3) & 7); }
// LDS byte-address swizzle: spreads 1KB..8KB row strides over banks (involution)
__device__ __forceinline__ int actswz(int a) {
    return a ^ ((((a >> 10) ^ (a >> 13)) & 7) << 4);
}

#define GLD16(g, l)                                                        \
    __builtin_amdgcn_global_load_lds(                                      \
        (const __attribute__((address_space(1))) void*)(g),                \
        (__attribute__((address_space(3))) void*)(l), 16, 0, 0)

#define WAITV3() asm volatile("s_waitcnt vmcnt(3)" ::: "memory")
#define WAITV0() asm volatile("s_waitcnt vmcnt(0)" ::: "memory")
#define BAR() __builtin_amdgcn_s_barrier()

// ---------------------------------------------------------------------------
// Setup: blocks 0..7999 table f32->bf16; 8000..8063 Wfrag (MFMA frag order);
// 8064..8127 WFwT transpose (f32).
__global__ void __launch_bounds__(256) setup_kernel(const float* __restrict__ table,
                                                    const float* __restrict__ WRw,
                                                    const float* __restrict__ WFw,
                                                    bf16_t* __restrict__ tableBf,
                                                    bf16_t* __restrict__ Wfrag,
                                                    float* __restrict__ WFwT) {
    const int b = blockIdx.x, tid = threadIdx.x;
    if (b < 8000) {
        int i = b * 256 + tid;
        float4 v = ((const float4*)table)[i];
        bf16x4 o;
        o[0] = f2bf(v.x); o[1] = f2bf(v.y); o[2] = f2bf(v.z); o[3] = f2bf(v.w);
        ((bf16x4*)tableBf)[i] = o;
    } else if (b < 8064) {
        int gt = (b - 8000) * 256 + tid;        // 0..16383
        int n16 = gt >> 10, rem = gt & 1023;
        int kt = rem >> 6, ln = rem & 63;
        int r = n16 * 16 + (ln & 15);
        int c = kt * 32 + (ln >> 4) * 8;
        const float4* s = (const float4*)(WRw + (long)r * 512 + c);
        float4 v0 = s[0], v1 = s[1];
        bf16x8 o;
        o[0] = f2bf(v0.x); o[1] = f2bf(v0.y); o[2] = f2bf(v0.z); o[3] = f2bf(v0.w);
        o[4] = f2bf(v1.x); o[5] = f2bf(v1.y); o[6] = f2bf(v1.z); o[7] = f2bf(v1.w);
        *(bf16x8*)(Wfrag + (size_t)gt * 8) = o;
    } else {
        int i0 = (b - 8064) * 1024 + tid * 4;   // WFwT[k*256+t] = WFw[t*256+k]
        float4 v;
        v.x = WFw[((i0 + 0) & 255) * 256 + ((i0 + 0) >> 8)];
        v.y = WFw[((i0 + 1) & 255) * 256 + ((i0 + 1) >> 8)];
        v.z = WFw[((i0 + 2) & 255) * 256 + ((i0 + 2) >> 8)];
        v.w = WFw[((i0 + 3) & 255) * 256 + ((i0 + 3) >> 8)];
        *(float4*)(WFwT + i0) = v;
    }
}

// ---------------------------------------------------------------------------
// Fully fused tree: 256 blocks (one batch each), 512 threads (8 waves).
// Wave w owns output cols [32w, 32w+32) at EVERY level. ALL levels stream W
// fragments from global (coalesced 1KB/wave/frag, L2-hot, ~16 VGPRs in
// flight). No wreg[2][16]: 8-wave blocks cap the unified reg file at 256/wave
// (128 arch + 128 acc split) and a 128-VGPR resident W array forced 44MB of
// scratch spill in rounds 6-8.
__global__ void __launch_bounds__(512) fused_kernel(const int* __restrict__ tokens,
                                                    const bf16_t* __restrict__ tableBf,
                                                    const bf16_t* __restrict__ Wfrag,
                                                    const float* __restrict__ bias,
                                                    const float* __restrict__ WFwT,
                                                    const float* __restrict__ WFb,
                                                    const float* __restrict__ WOw,
                                                    const float* __restrict__ WOb,
                                                    float* __restrict__ out) {
    __shared__ __align__(16) char stg[24576];    // 3 x 8KB A-staging
    __shared__ __align__(16) char bufX[65536];   // L1-out half: 64 A-rows x 1KB
    __shared__ __align__(16) char act[65536];    // L2-out + tail levels
    __shared__ float hid[256];

    const int tid = threadIdx.x, lane = tid & 63, w = tid >> 6;
    const int lr = lane & 15, g = lane >> 4, crow = g << 2;
    const f32x4 zero = {0.f, 0.f, 0.f, 0.f};

    float bvT[2];
#pragma unroll
    for (int nt = 0; nt < 2; ++nt) bvT[nt] = bias[(w << 5) + (nt << 4) + lr];

    // W fragment source: frag(kt,nt) of wave w = wfW + nt*8192 + kt*512
    const bf16_t* wfW = Wfrag + (size_t)w * 16384 + (size_t)lane * 8;
    auto ldW = [&](int kt, int nt) {
        return *(const bf16x8*)(wfW + nt * 8192 + kt * 512);
    };

    // L1 staging geometry (8KB tile = 512 units of 16B; unit-swizzled source)
    const int us = (w << 6) + swz(lane);
    const int srow = us >> 2;              // A-row within half, 0..127
    const int scolE = (us & 3) << 3;       // elem offset 0,8,16,24
    char* dst = stg + (w << 10);
    int offA1[8];
#pragma unroll
    for (int mt = 0; mt < 8; ++mt)
        offA1[mt] = swz((((mt << 4) + lr) << 2) + g) << 4;

    // ================= L1 + L2, two halves ================================
#pragma unroll 1
    for (int h = 0; h < 2; ++h) {
        long mrow = (long)blockIdx.x * 256 + h * 128 + srow;
        int tok0 = tokens[2 * mrow], tok1 = tokens[2 * mrow + 1];
        const bf16_t* tLo = tableBf + (long)tok0 * 256 + scolE;
        const bf16_t* tHi = tableBf + (long)tok1 * 256 + scolE;

        auto stage = [&](int s, int kt) {
            const bf16_t* src = (kt < 8) ? (tLo + (kt << 5)) : (tHi + ((kt - 8) << 5));
            GLD16(src, dst + s * 8192);
        };

        f32x4 acc[8][2];
#pragma unroll
        for (int i = 0; i < 8; ++i) { acc[i][0] = zero; acc[i][1] = zero; }

        stage(0, 0); stage(1, 1);
        bf16x8 wfa = ldW(0, 0), wfb = ldW(0, 1);
        WAITV3(); BAR();                    // S(0) landed; {S1,Wa0,Wb0} in flight
#pragma unroll
        for (int t = 0; t < 16; ++t) {
            bf16x8 wfa_n, wfb_n;
            if (t + 1 < 16) { wfa_n = ldW(t + 1, 0); wfb_n = ldW(t + 1, 1); }
            if (t + 2 < 16) stage((t + 2) % 3, t + 2);
            const char* base = stg + (t % 3) * 8192;
            bf16x8 af[8];
#pragma unroll
            for (int mt = 0; mt < 8; ++mt) af[mt] = *(const bf16x8*)(base + offA1[mt]);
#pragma unroll
            for (int mt = 0; mt < 8; ++mt) {
                acc[mt][0] = __builtin_amdgcn_mfma_f32_16x16x32_bf16(af[mt], wfa, acc[mt][0], 0, 0, 0);
                acc[mt][1] = __builtin_amdgcn_mfma_f32_16x16x32_bf16(af[mt], wfb, acc[mt][1], 0, 0, 0);
            }
            if (t < 14)       { WAITV3(); BAR(); }   // S(t+1) landed, 3 newest in flight
            else if (t == 14) { WAITV0(); BAR(); }
            wfa = wfa_n; wfb = wfb_n;
        }
        // L1 epilogue -> bufX: L1 row r at byte (r>>1)*1024 + (r&1)*512
#pragma unroll
        for (int nt = 0; nt < 2; ++nt) {
            int col = (w << 5) + (nt << 4) + lr;
#pragma unroll
            for (int mt = 0; mt < 8; ++mt)
#pragma unroll
                for (int rr = 0; rr < 4; ++rr) {
                    int r = (mt << 4) + crow + rr;
                    int a = ((r >> 1) << 10) + ((r & 1) << 9) + (col << 1);
                    *(bf16_t*)(bufX + actswz(a)) =
                        f2bf(tanh_fast(acc[mt][nt][rr] + bvT[nt]));
                }
        }
        __syncthreads();

        // L2 half: M=64 (out rows h*64..), A = bufX 1KB rows, W streamed
        f32x4 acc2[4][2];
#pragma unroll
        for (int i = 0; i < 4; ++i) { acc2[i][0] = zero; acc2[i][1] = zero; }
#pragma unroll
        for (int kt = 0; kt < 16; ++kt) {
            bf16x8 wa = ldW(kt, 0), wb = ldW(kt, 1);
#pragma unroll
            for (int mt = 0; mt < 4; ++mt) {
                int a = (((mt << 4) + lr) << 10) + (kt << 6) + (g << 4);
                bf16x8 af = *(const bf16x8*)(bufX + actswz(a));
                acc2[mt][0] = __builtin_amdgcn_mfma_f32_16x16x32_bf16(af, wa, acc2[mt][0], 0, 0, 0);
                acc2[mt][1] = __builtin_amdgcn_mfma_f32_16x16x32_bf16(af, wb, acc2[mt][1], 0, 0, 0);
            }
        }
        __syncthreads();       // all bufX reads done before next half overwrites
#pragma unroll
        for (int nt = 0; nt < 2; ++nt) {
            int col = (w << 5) + (nt << 4) + lr;
#pragma unroll
            for (int mt = 0; mt < 4; ++mt)
#pragma unroll
                for (int rr = 0; rr < 4; ++rr) {
                    int q = (h << 6) + (mt << 4) + crow + rr;   // 0..127
                    int a = (q << 9) + (col << 1);
                    *(bf16_t*)(act + actswz(a)) =
                        f2bf(tanh_fast(acc2[mt][nt][rr] + bvT[nt]));
                }
        }
        __syncthreads();
    }

    // ================= L3: M=64, A rows at 1KB stride, W streamed ==========
    {
        f32x4 acc[4][2];
#pragma unroll
        for (int i = 0; i < 4; ++i) { acc[i][0] = zero; acc[i][1] = zero; }
#pragma unroll
        for (int kt = 0; kt < 16; ++kt) {
            bf16x8 wa = ldW(kt, 0), wb = ldW(kt, 1);
#pragma unroll
            for (int mt = 0; mt < 4; ++mt) {
                int a = (((mt << 4) + lr) << 10) + (kt << 6) + (g << 4);
                bf16x8 af = *(const bf16x8*)(act + actswz(a));
                acc[mt][0] = __builtin_amdgcn_mfma_f32_16x16x32_bf16(af, wa, acc[mt][0], 0, 0, 0);
                acc[mt][1] = __builtin_amdgcn_mfma_f32_16x16x32_bf16(af, wb, acc[mt][1], 0, 0, 0);
            }
        }
        __syncthreads();
#pragma unroll
        for (int nt = 0; nt < 2; ++nt) {
            int col = (w << 5) + (nt << 4) + lr;
#pragma unroll
            for (int mt = 0; mt < 4; ++mt)
#pragma unroll
                for (int rr = 0; rr < 4; ++rr) {
                    int q = (mt << 4) + crow + rr;              // 0..63
                    int a = (q << 10) + (col << 1);
                    *(bf16_t*)(act + actswz(a)) =
                        f2bf(tanh_fast(acc[mt][nt][rr] + bvT[nt]));
                }
        }
        __syncthreads();
    }

    // ================= L4: M=32, W streamed ================================
    {
        f32x4 acc[2][2];
#pragma unroll
        for (int i = 0; i < 2; ++i) { acc[i][0] = zero; acc[i][1] = zero; }
#pragma unroll
        for (int kt = 0; kt < 16; ++kt) {
            bf16x8 wa = ldW(kt, 0), wb = ldW(kt, 1);
#pragma unroll
            for (int mt = 0; mt < 2; ++mt) {
                int row = (mt << 4) + lr;                       // 0..31
                int a = (row << 11) + ((kt >= 8) ? 1024 : 0) + ((kt & 7) << 6) + (g << 4);
                bf16x8 af = *(const bf16x8*)(act + actswz(a));
                acc[mt][0] = __builtin_amdgcn_mfma_f32_16x16x32_bf16(af, wa, acc[mt][0], 0, 0, 0);
                acc[mt][1] = __builtin_amdgcn_mfma_f32_16x16x32_bf16(af, wb, acc[mt][1], 0, 0, 0);
            }
        }
        __syncthreads();
#pragma unroll
        for (int nt = 0; nt < 2; ++nt) {
            int col = (w << 5) + (nt << 4) + lr;
#pragma unroll
            for (int mt = 0; mt < 2; ++mt)
#pragma unroll
                for (int rr = 0; rr < 4; ++rr) {
                    int q = (mt << 4) + crow + rr;              // 0..31
                    int a = (q << 11) + (col << 1);
                    *(bf16_t*)(act + actswz(a)) =
                        f2bf(tanh_fast(acc[mt][nt][rr] + bvT[nt]));
                }
        }
        __syncthreads();
    }

    // ================= L5..L9: M=16 padded, W streamed (L2-hot) ============
#pragma unroll 1
    for (int lev = 0; lev < 5; ++lev) {
        const int sA = 4096 << lev;
        const int half_ = sA >> 1;
        f32x4 acc[2];
        acc[0] = zero; acc[1] = zero;
#pragma unroll
        for (int kt = 0; kt < 16; ++kt) {
            bf16x8 wa = ldW(kt, 0), wb = ldW(kt, 1);
            int a = (sA * lr + ((kt >= 8) ? half_ : 0) + ((kt & 7) << 6) + (g << 4)) & 65535;
            bf16x8 af = *(const bf16x8*)(act + actswz(a));
            acc[0] = __builtin_amdgcn_mfma_f32_16x16x32_bf16(af, wa, acc[0], 0, 0, 0);
            acc[1] = __builtin_amdgcn_mfma_f32_16x16x32_bf16(af, wb, acc[1], 0, 0, 0);
        }
        __syncthreads();
        const int valid = 16 >> lev;
#pragma unroll
        for (int nt = 0; nt < 2; ++nt) {
            int col = (w << 5) + (nt << 4) + lr;
#pragma unroll
            for (int rr = 0; rr < 4; ++rr) {
                int m0 = crow + rr;
                if (m0 < valid) {
                    int a = sA * m0 + (col << 1);
                    *(bf16_t*)(act + actswz(a)) =
                        f2bf(tanh_fast(acc[nt][rr] + bvT[nt]));
                }
            }
        }
        __syncthreads();
    }

    // ================= head: root = act[0..512) (swizzle-free region) ======
    if (tid < 256) {
        const bf16_t* root = (const bf16_t*)act;
        float s = WFb[tid];
#pragma unroll 8
        for (int k = 0; k < 256; ++k)
            s += (float)root[k] * WFwT[k * 256 + tid];
        hid[tid] = fmaxf(s, 0.0f);
    }
    __syncthreads();

    if (w < 5) {
        const float* wo = WOw + w * 256;
        float p = hid[lane] * wo[lane] + hid[lane + 64] * wo[lane + 64] +
                  hid[lane + 128] * wo[lane + 128] + hid[lane + 192] * wo[lane + 192];
#pragma unroll
        for (int off = 32; off > 0; off >>= 1) p += __shfl_down(p, off);
        if (lane == 0) out[(long)blockIdx.x * 5 + w] = p + WOb[w];
    }
}

// ---------------------------------------------------------------------------
extern "C" void kernel_launch(void* const* d_in, const int* in_sizes, int n_in,
                              void* d_out, int out_size, void* d_ws, size_t ws_size,
                              hipStream_t stream) {
    const int*   tokens = (const int*)d_in[0];
    const float* table  = (const float*)d_in[1];
    const float* WRw    = (const float*)d_in[2];
    const float* WRb    = (const float*)d_in[3];
    const float* WFw    = (const float*)d_in[4];
    const float* WFb    = (const float*)d_in[5];
    const float* WOw    = (const float*)d_in[6];
    const float* WOb    = (const float*)d_in[7];
    float* out = (float*)d_out;

    char* ws = (char*)d_ws;
    bf16_t* tableBf = (bf16_t*)ws;                        // 16.4 MB
    bf16_t* Wfrag = (bf16_t*)(ws + (size_t)20971520);     // 256 KB
    float*  WFwT  = (float*)(ws + (size_t)22020096);      // 256 KB

    setup_kernel<<<8128, 256, 0, stream>>>(table, WRw, WFw, tableBf, Wfrag, WFwT);
    fused_kernel<<<256, 512, 0, stream>>>(tokens, tableBf, Wfrag, WRb, WFwT,
                                          WFb, WOw, WOb, out);
}

// Round 11
// 155.012 us; speedup vs baseline: 1.4569x; 1.3185x over previous
//
#include <hip/hip_runtime.h>
#include <hip/hip_bf16.h>

typedef __bf16 bf16_t;
typedef __bf16 bf16x8 __attribute__((ext_vector_type(8)));
typedef __bf16 bf16x4 __attribute__((ext_vector_type(4)));
typedef float f32x4 __attribute__((ext_vector_type(4)));

__device__ __forceinline__ bf16_t f2bf(float f) {
    __hip_bfloat16 h = __float2bfloat16(f);   // RNE
    return __builtin_bit_cast(bf16_t, h);
}

__device__ __forceinline__ float tanh_fast(float s) {
    float e2x = __expf(2.0f * s);
    return 1.0f - 2.0f * __builtin_amdgcn_rcpf(e2x + 1.0f);
}

// 16B-unit XOR swizzle within 64-unit groups (involution)
__device__ __forceinline__ int swz(int u) { return u ^ ((u >> 3) & 7); }
// LDS byte-address swizzle: spreads 512B..8KB row strides over banks (involution)
__device__ __forceinline__ int actswz(int a) {
    return a ^ ((((a >> 10) ^ (a >> 13)) & 7) << 4);
}

#define GLD16(g, l)                                                        \
    __builtin_amdgcn_global_load_lds(                                      \
        (const __attribute__((address_space(1))) void*)(g),                \
        (__attribute__((address_space(3))) void*)(l), 16, 0, 0)

#define WAITV5() asm volatile("s_waitcnt vmcnt(5)" ::: "memory")
#define WAITV0() asm volatile("s_waitcnt vmcnt(0)" ::: "memory")
#define BAR() __builtin_amdgcn_s_barrier()

// ---------------------------------------------------------------------------
// Setup: blocks 0..7999 table f32->bf16; 8000..8063 Wfrag (MFMA frag order);
// 8064..8127 WFwT transpose (f32).
__global__ void __launch_bounds__(256) setup_kernel(const float* __restrict__ table,
                                                    const float* __restrict__ WRw,
                                                    const float* __restrict__ WFw,
                                                    bf16_t* __restrict__ tableBf,
                                                    bf16_t* __restrict__ Wfrag,
                                                    float* __restrict__ WFwT) {
    const int b = blockIdx.x, tid = threadIdx.x;
    if (b < 8000) {
        int i = b * 256 + tid;
        float4 v = ((const float4*)table)[i];
        bf16x4 o;
        o[0] = f2bf(v.x); o[1] = f2bf(v.y); o[2] = f2bf(v.z); o[3] = f2bf(v.w);
        ((bf16x4*)tableBf)[i] = o;
    } else if (b < 8064) {
        int gt = (b - 8000) * 256 + tid;        // 0..16383
        int n16 = gt >> 10, rem = gt & 1023;
        int kt = rem >> 6, ln = rem & 63;
        int r = n16 * 16 + (ln & 15);
        int c = kt * 32 + (ln >> 4) * 8;
        const float4* s = (const float4*)(WRw + (long)r * 512 + c);
        float4 v0 = s[0], v1 = s[1];
        bf16x8 o;
        o[0] = f2bf(v0.x); o[1] = f2bf(v0.y); o[2] = f2bf(v0.z); o[3] = f2bf(v0.w);
        o[4] = f2bf(v1.x); o[5] = f2bf(v1.y); o[6] = f2bf(v1.z); o[7] = f2bf(v1.w);
        *(bf16x8*)(Wfrag + (size_t)gt * 8) = o;
    } else {
        int i0 = (b - 8064) * 1024 + tid * 4;   // WFwT[k*256+t] = WFw[t*256+k]
        float4 v;
        v.x = WFw[((i0 + 0) & 255) * 256 + ((i0 + 0) >> 8)];
        v.y = WFw[((i0 + 1) & 255) * 256 + ((i0 + 1) >> 8)];
        v.z = WFw[((i0 + 2) & 255) * 256 + ((i0 + 2) >> 8)];
        v.w = WFw[((i0 + 3) & 255) * 256 + ((i0 + 3) >> 8)];
        *(float4*)(WFwT + i0) = v;
    }
}

// ---------------------------------------------------------------------------
// Fused tree, 256 blocks x 512 thr. L1 quartered (64 rows/pass, acc[4][2]=32
// regs) to fit the 128-VGPR allocation WITHOUT scratch spill (rounds 6-10:
// acc[8][2]+af[8] overflowed -> 44MB scratch traffic, 2/3 of runtime).
// Wave w owns cols [32w,32w+32) at every level; W streamed from L2.
__global__ void __launch_bounds__(512) fused_kernel(const int* __restrict__ tokens,
                                                    const bf16_t* __restrict__ tableBf,
                                                    const bf16_t* __restrict__ Wfrag,
                                                    const float* __restrict__ bias,
                                                    const float* __restrict__ WFwT,
                                                    const float* __restrict__ WFb,
                                                    const float* __restrict__ WOw,
                                                    const float* __restrict__ WOb,
                                                    float* __restrict__ out) {
    __shared__ __align__(16) char stg[24576];    // 3 x 8KB A-staging
    __shared__ __align__(16) char bufX[32768];   // L1-out quarter: 32 A-rows x 1KB
    __shared__ __align__(16) char act[65536];    // L2-out + tail levels
    __shared__ float hid[256];

    const int tid = threadIdx.x, lane = tid & 63, w = tid >> 6;
    const int lr = lane & 15, g = lane >> 4, crow = g << 2;
    const f32x4 zero = {0.f, 0.f, 0.f, 0.f};

    float bvT[2];
#pragma unroll
    for (int nt = 0; nt < 2; ++nt) bvT[nt] = bias[(w << 5) + (nt << 4) + lr];

    // W fragment source: frag(kt,nt) of wave w = wfW + nt*8192 + kt*512
    const bf16_t* wfW = Wfrag + (size_t)w * 16384 + (size_t)lane * 8;
    auto ldW = [&](int kt, int nt) {
        return *(const bf16x8*)(wfW + nt * 8192 + kt * 512);
    };

    // L1 staging geometry: tile = 64 rows x 64 cols (8KB, BK=64) = 512 units
    const int us = (w << 6) + swz(lane);
    const int srow = us >> 3;              // row 0..63
    const int scolE = (us & 7) << 3;       // col elem 0..56
    char* dst = stg + (w << 10);
    // A-frag read: addr = mt*2048 + lr*128 + ((s*4+g)^(lr&7))*16
    const int aB0 = lr * 128 + ((g ^ (lr & 7)) << 4);
    const int aB1 = lr * 128 + (((4 + g) ^ (lr & 7)) << 4);

    // ================= L1 + L2, four quarters of 64 L1-rows ===============
#pragma unroll 1
    for (int q = 0; q < 4; ++q) {
        long mrow = (long)blockIdx.x * 256 + q * 64 + srow;
        int tok0 = tokens[2 * mrow], tok1 = tokens[2 * mrow + 1];
        const bf16_t* tLo = tableBf + (long)tok0 * 256 + scolE;
        const bf16_t* tHi = tableBf + (long)tok1 * 256 + scolE;

        auto stage = [&](int s, int kt) {   // kt in [0,8): 64-col block
            const bf16_t* src = (kt < 4) ? (tLo + (kt << 6)) : (tHi + ((kt - 4) << 6));
            GLD16(src, dst + s * 8192);
        };

        f32x4 acc[4][2];
#pragma unroll
        for (int i = 0; i < 4; ++i) { acc[i][0] = zero; acc[i][1] = zero; }

        stage(0, 0); stage(1, 1);
        bf16x8 w0a = ldW(0, 0), w0b = ldW(0, 1), w1a = ldW(1, 0), w1b = ldW(1, 1);
        WAITV5(); BAR();                    // S0 landed; S1 + W(0)x4 in flight
#pragma unroll
        for (int t = 0; t < 8; ++t) {
            bf16x8 n0a, n0b, n1a, n1b;
            if (t + 1 < 8) {
                n0a = ldW(2 * t + 2, 0); n0b = ldW(2 * t + 2, 1);
                n1a = ldW(2 * t + 3, 0); n1b = ldW(2 * t + 3, 1);
            }
            if (t + 2 < 8) stage((t + 2) % 3, t + 2);
            const char* base = stg + (t % 3) * 8192;
#pragma unroll
            for (int mt = 0; mt < 4; ++mt) {      // sub-step s=0 (cols t*64..+31)
                bf16x8 af = *(const bf16x8*)(base + mt * 2048 + aB0);
                acc[mt][0] = __builtin_amdgcn_mfma_f32_16x16x32_bf16(af, w0a, acc[mt][0], 0, 0, 0);
                acc[mt][1] = __builtin_amdgcn_mfma_f32_16x16x32_bf16(af, w0b, acc[mt][1], 0, 0, 0);
            }
#pragma unroll
            for (int mt = 0; mt < 4; ++mt) {      // sub-step s=1 (cols t*64+32..+63)
                bf16x8 af = *(const bf16x8*)(base + mt * 2048 + aB1);
                acc[mt][0] = __builtin_amdgcn_mfma_f32_16x16x32_bf16(af, w1a, acc[mt][0], 0, 0, 0);
                acc[mt][1] = __builtin_amdgcn_mfma_f32_16x16x32_bf16(af, w1b, acc[mt][1], 0, 0, 0);
            }
            if (t < 6)       { WAITV5(); BAR(); }  // S(t+1) landed; W(t+1)x4+S(t+2) fly
            else if (t == 6) { WAITV0(); BAR(); }
            w0a = n0a; w0b = n0b; w1a = n1a; w1b = n1b;
        }
        // L1 epilogue -> bufX: quarter-local L1 row r at (r>>1)*1024+(r&1)*512
#pragma unroll
        for (int nt = 0; nt < 2; ++nt) {
            int col = (w << 5) + (nt << 4) + lr;
#pragma unroll
            for (int mt = 0; mt < 4; ++mt)
#pragma unroll
                for (int rr = 0; rr < 4; ++rr) {
                    int r = (mt << 4) + crow + rr;          // 0..63
                    int a = ((r >> 1) << 10) + ((r & 1) << 9) + (col << 1);
                    *(bf16_t*)(bufX + actswz(a)) =
                        f2bf(tanh_fast(acc[mt][nt][rr] + bvT[nt]));
                }
        }
        __syncthreads();

        // L2 quarter: M=32 (A = bufX rows 0..31 at 1KB), W streamed
        f32x4 acc2[2][2];
#pragma unroll
        for (int i = 0; i < 2; ++i) { acc2[i][0] = zero; acc2[i][1] = zero; }
#pragma unroll
        for (int kt = 0; kt < 16; ++kt) {
            bf16x8 wa = ldW(kt, 0), wb = ldW(kt, 1);
#pragma unroll
            for (int mt = 0; mt < 2; ++mt) {
                int a = (((mt << 4) + lr) << 10) + (kt << 6) + (g << 4);
                bf16x8 af = *(const bf16x8*)(bufX + actswz(a));
                acc2[mt][0] = __builtin_amdgcn_mfma_f32_16x16x32_bf16(af, wa, acc2[mt][0], 0, 0, 0);
                acc2[mt][1] = __builtin_amdgcn_mfma_f32_16x16x32_bf16(af, wb, acc2[mt][1], 0, 0, 0);
            }
        }
        // L2 epilogue -> act rows q*32..q*32+31 (512B rows)
#pragma unroll
        for (int nt = 0; nt < 2; ++nt) {
            int col = (w << 5) + (nt << 4) + lr;
#pragma unroll
            for (int mt = 0; mt < 2; ++mt)
#pragma unroll
                for (int rr = 0; rr < 4; ++rr) {
                    int qrow = (q << 5) + (mt << 4) + crow + rr;   // 0..127
                    int a = (qrow << 9) + (col << 1);
                    *(bf16_t*)(act + actswz(a)) =
                        f2bf(tanh_fast(acc2[mt][nt][rr] + bvT[nt]));
                }
        }
        __syncthreads();   // bufX reads done before next quarter overwrites
    }

    // ================= L3: M=64, A rows at 1KB stride, W streamed ==========
    {
        f32x4 acc[4][2];
#pragma unroll
        for (int i = 0; i < 4; ++i) { acc[i][0] = zero; acc[i][1] = zero; }
#pragma unroll
        for (int kt = 0; kt < 16; ++kt) {
            bf16x8 wa = ldW(kt, 0), wb = ldW(kt, 1);
#pragma unroll
            for (int mt = 0; mt < 4; ++mt) {
                int a = (((mt << 4) + lr) << 10) + (kt << 6) + (g << 4);
                bf16x8 af = *(const bf16x8*)(act + actswz(a));
                acc[mt][0] = __builtin_amdgcn_mfma_f32_16x16x32_bf16(af, wa, acc[mt][0], 0, 0, 0);
                acc[mt][1] = __builtin_amdgcn_mfma_f32_16x16x32_bf16(af, wb, acc[mt][1], 0, 0, 0);
            }
        }
        __syncthreads();
#pragma unroll
        for (int nt = 0; nt < 2; ++nt) {
            int col = (w << 5) + (nt << 4) + lr;
#pragma unroll
            for (int mt = 0; mt < 4; ++mt)
#pragma unroll
                for (int rr = 0; rr < 4; ++rr) {
                    int qrow = (mt << 4) + crow + rr;           // 0..63
                    int a = (qrow << 10) + (col << 1);
                    *(bf16_t*)(act + actswz(a)) =
                        f2bf(tanh_fast(acc[mt][nt][rr] + bvT[nt]));
                }
        }
        __syncthreads();
    }

    // ================= L4: M=32, W streamed ================================
    {
        f32x4 acc[2][2];
#pragma unroll
        for (int i = 0; i < 2; ++i) { acc[i][0] = zero; acc[i][1] = zero; }
#pragma unroll
        for (int kt = 0; kt < 16; ++kt) {
            bf16x8 wa = ldW(kt, 0), wb = ldW(kt, 1);
#pragma unroll
            for (int mt = 0; mt < 2; ++mt) {
                int row = (mt << 4) + lr;                       // 0..31
                int a = (row << 11) + ((kt >= 8) ? 1024 : 0) + ((kt & 7) << 6) + (g << 4);
                bf16x8 af = *(const bf16x8*)(act + actswz(a));
                acc[mt][0] = __builtin_amdgcn_mfma_f32_16x16x32_bf16(af, wa, acc[mt][0], 0, 0, 0);
                acc[mt][1] = __builtin_amdgcn_mfma_f32_16x16x32_bf16(af, wb, acc[mt][1], 0, 0, 0);
            }
        }
        __syncthreads();
#pragma unroll
        for (int nt = 0; nt < 2; ++nt) {
            int col = (w << 5) + (nt << 4) + lr;
#pragma unroll
            for (int mt = 0; mt < 2; ++mt)
#pragma unroll
                for (int rr = 0; rr < 4; ++rr) {
                    int qrow = (mt << 4) + crow + rr;           // 0..31
                    int a = (qrow << 11) + (col << 1);
                    *(bf16_t*)(act + actswz(a)) =
                        f2bf(tanh_fast(acc[mt][nt][rr] + bvT[nt]));
                }
        }
        __syncthreads();
    }

    // ================= L5..L9: M=16 padded, W streamed (L2-hot) ============
#pragma unroll 1
    for (int lev = 0; lev < 5; ++lev) {
        const int sA = 4096 << lev;
        const int half_ = sA >> 1;
        f32x4 acc[2];
        acc[0] = zero; acc[1] = zero;
#pragma unroll
        for (int kt = 0; kt < 16; ++kt) {
            bf16x8 wa = ldW(kt, 0), wb = ldW(kt, 1);
            int a = (sA * lr + ((kt >= 8) ? half_ : 0) + ((kt & 7) << 6) + (g << 4)) & 65535;
            bf16x8 af = *(const bf16x8*)(act + actswz(a));
            acc[0] = __builtin_amdgcn_mfma_f32_16x16x32_bf16(af, wa, acc[0], 0, 0, 0);
            acc[1] = __builtin_amdgcn_mfma_f32_16x16x32_bf16(af, wb, acc[1], 0, 0, 0);
        }
        __syncthreads();
        const int valid = 16 >> lev;
#pragma unroll
        for (int nt = 0; nt < 2; ++nt) {
            int col = (w << 5) + (nt << 4) + lr;
#pragma unroll
            for (int rr = 0; rr < 4; ++rr) {
                int m0 = crow + rr;
                if (m0 < valid) {
                    int a = sA * m0 + (col << 1);
                    *(bf16_t*)(act + actswz(a)) =
                        f2bf(tanh_fast(acc[nt][rr] + bvT[nt]));
                }
            }
        }
        __syncthreads();
    }

    // ================= head: root = act[0..512) (swizzle-free region) ======
    if (tid < 256) {
        const bf16_t* root = (const bf16_t*)act;
        float s = WFb[tid];
#pragma unroll 8
        for (int k = 0; k < 256; ++k)
            s += (float)root[k] * WFwT[k * 256 + tid];
        hid[tid] = fmaxf(s, 0.0f);
    }
    __syncthreads();

    if (w < 5) {
        const float* wo = WOw + w * 256;
        float p = hid[lane] * wo[lane] + hid[lane + 64] * wo[lane + 64] +
                  hid[lane + 128] * wo[lane + 128] + hid[lane + 192] * wo[lane + 192];
#pragma unroll
        for (int off = 32; off > 0; off >>= 1) p += __shfl_down(p, off);
        if (lane == 0) out[(long)blockIdx.x * 5 + w] = p + WOb[w];
    }
}

// ---------------------------------------------------------------------------
extern "C" void kernel_launch(void* const* d_in, const int* in_sizes, int n_in,
                              void* d_out, int out_size, void* d_ws, size_t ws_size,
                              hipStream_t stream) {
    const int*   tokens = (const int*)d_in[0];
    const float* table  = (const float*)d_in[1];
    const float* WRw    = (const float*)d_in[2];
    const float* WRb    = (const float*)d_in[3];
    const float* WFw    = (const float*)d_in[4];
    const float* WFb    = (const float*)d_in[5];
    const float* WOw    = (const float*)d_in[6];
    const float* WOb    = (const float*)d_in[7];
    float* out = (float*)d_out;

    char* ws = (char*)d_ws;
    bf16_t* tableBf = (bf16_t*)ws;                        // 16.4 MB
    bf16_t* Wfrag = (bf16_t*)(ws + (size_t)20971520);     // 256 KB
    float*  WFwT  = (float*)(ws + (size_t)22020096);      // 256 KB

    setup_kernel<<<8128, 256, 0, stream>>>(table, WRw, WFw, tableBf, Wfrag, WFwT);
    fused_kernel<<<256, 512, 0, stream>>>(tokens, tableBf, Wfrag, WRb, WFwT,
                                          WFb, WOw, WOb, out);
}